// Round 3
// baseline (803.821 us; speedup 1.0000x reference)
//
#include <hip/hip_runtime.h>

// Problem constants (B=8, C=64, W=496, H=432)
#define WH      214272            // 496*432 pixels per (b,c) plane
#define GPB     53568             // WH/4 float4 groups per plane (mult of 64)
#define TOTAL4  (512*GPB)         // all float4 elements = 27,426,816
#define CHUNKS  (TOTAL4/64)       // 64-float4 (1 KB/wave) chunks = 428544
#define CPP     (GPB/64)          // chunks per plane = 837

#define BLOCKS  2048              // 8 blocks/CU, 32 waves/CU for BOTH kernels
#define NW      (BLOCKS*4)        // 8192 waves
#define PER     ((CHUNKS + NW - 1)/NW)   // 53 chunks per wave run

typedef float floatx4 __attribute__((ext_vector_type(4)));

// ---------------- K1: per-channel sum/sumsq + per-batch mask count ----------------
// Contiguous per-wave runs (known-good round-0 structure), now at 32 waves/CU for
// latency hiding (was 16 -> 2.6 TB/s; copy ceiling is 6.3). Each wave owns 53
// contiguous 1KB chunks; channel is wave-uniform within a plane-run (53 < 837 so
// <=2 plane-runs/wave) -> scalar accumulators, butterfly reduce + 2 atomics per run.
// Mask: occ zeroes all channels of a pixel together -> channel 0 alone decides.
__global__ __launch_bounds__(256, 8) void k_stats(const floatx4* __restrict__ x4,
                                                  float* __restrict__ gsum,
                                                  float* __restrict__ gsq,
                                                  int* __restrict__ gn) {
    const int lane = threadIdx.x & 63;
    const int gw   = blockIdx.x * 4 + (threadIdx.x >> 6);   // global wave id
    int c0 = gw * PER;
    const int c1 = min(c0 + PER, CHUNKS);

    while (c0 < c1) {
        const int plane = (int)((unsigned)c0 / CPP);        // wave-uniform
        const int run   = min(c1, (plane + 1) * CPP);       // end of this plane-run
        const bool isC0 = (plane & 63) == 0;

        float s = 0.f, q = 0.f;
        int cnt = 0;
        const floatx4* p = x4 + (size_t)c0 * 64 + lane;
        const int n = run - c0;
#pragma unroll 4
        for (int k = 0; k < n; ++k) {
            const floatx4 v = p[(size_t)k * 64];
            s += (v.x + v.y) + (v.z + v.w);
            q = fmaf(v.w, v.w, fmaf(v.z, v.z, fmaf(v.y, v.y, fmaf(v.x, v.x, q))));
            if (isC0) cnt += (v.x != 0.f) + (v.y != 0.f) + (v.z != 0.f) + (v.w != 0.f);
        }
#pragma unroll
        for (int m = 1; m < 64; m <<= 1) {
            s += __shfl_xor(s, m, 64);
            q += __shfl_xor(q, m, 64);
        }
        if (isC0) {
#pragma unroll
            for (int m = 1; m < 64; m <<= 1) cnt += __shfl_xor(cnt, m, 64);
        }
        if (lane == 0) {
            atomicAdd(&gsum[plane & 63], s);
            atomicAdd(&gsq[plane & 63], q);
            if (isC0) atomicAdd(&gn[plane >> 6], cnt);
        }
        c0 = run;
    }
}

// ---------------- K2: finalize (prologue) + out = x * inv[c] ------------------------
// PLAIN loads and PLAIN stores. The previous NT load/store pair ran at 1.44 TB/s
// (~610us, 77% of runtime, inferred from cross-round dispatch arithmetic): NT stores
// bypass L2 write-combining -> small write bursts + vmcnt store-serialization.
// Plain stores write-allocate in L2, burst back to HBM, and let the kernel retire
// before writeback drains. Wave gw mirrors stats wave gw's run, walked in reverse:
// if any of the stats run-tails survive in L3, they're consumed first (free upside).
__global__ __launch_bounds__(256, 8) void k_scale(const floatx4* __restrict__ x4,
                                                  floatx4* __restrict__ out4,
                                                  const float* __restrict__ gsum,
                                                  const float* __restrict__ gsq,
                                                  const int* __restrict__ gn) {
    __shared__ float sinv[64];
    const int tid = threadIdx.x;
    if (tid < 64) {
        const int c = tid;
        const float* x = (const float*)x4;
        int nb[8];
        int N = 0;
#pragma unroll
        for (int b = 0; b < 8; ++b) { nb[b] = gn[b]; N = max(N, nb[b]); }
        float total = gsum[c];
        float S2    = gsq[c];
#pragma unroll
        for (int b = 0; b < 8; ++b) {
            const float pad = (float)(N - nb[b]);
            const float x00 = x[(size_t)(b * 64 + c) * WH];
            total = fmaf(pad, x00, total);
            S2    = fmaf(pad, x00 * x00, S2);
        }
        const float count = (float)(8 * N);
        const float mean  = total / count;
        const float var   = S2 / count - mean * mean;
        sinv[c] = 1.0f / sqrtf(var + 0.001f);
    }
    __syncthreads();

    const int lane = tid & 63;
    const int gw   = blockIdx.x * 4 + (tid >> 6);   // 0..8191, mirrors stats wave
    const int c0   = gw * PER;
    const int c1   = min(c0 + PER, CHUNKS);
#pragma unroll 4
    for (int ch = c1 - 1; ch >= c0; --ch) {
        const int plane = (int)((unsigned)ch / CPP);      // wave-uniform
        const float inv = sinv[plane & 63];
        const size_t i = (size_t)ch * 64 + lane;
        floatx4 v = x4[i];
        v.x *= inv; v.y *= inv; v.z *= inv; v.w *= inv;
        out4[i] = v;
    }
}

extern "C" void kernel_launch(void* const* d_in, const int* in_sizes, int n_in,
                              void* d_out, int out_size, void* d_ws, size_t ws_size,
                              hipStream_t stream) {
    const float* x  = (const float*)d_in[0];
    float* out      = (float*)d_out;
    float* wsf      = (float*)d_ws;
    float* gsum     = wsf;               // 64 floats
    float* gsq      = wsf + 64;          // 64 floats
    int*   gn       = (int*)(wsf + 128); // 8 ints

    (void)hipMemsetAsync(d_ws, 0, 136 * sizeof(float), stream);

    k_stats<<<BLOCKS, 256, 0, stream>>>((const floatx4*)x, gsum, gsq, gn);
    k_scale<<<BLOCKS, 256, 0, stream>>>((const floatx4*)x, (floatx4*)out,
                                        gsum, gsq, gn);
}

// Round 4
// 765.348 us; speedup vs baseline: 1.0503x; 1.0503x over previous
//
#include <hip/hip_runtime.h>

// Problem constants (B=8, C=64, W=496, H=432)
#define WH      214272            // 496*432 pixels per (b,c) plane
#define GPB     53568             // WH/4 float4 groups per plane (mult of 64)
#define TOTAL4  (512*GPB)         // all float4 elements = 27,426,816
#define CHUNKS  (TOTAL4/64)       // 64-float4 (1 KB/wave) chunks = 428544
#define CPP     (GPB/64)          // chunks per plane = 837

#define STATS_BLOCKS 1024         // 4 blocks/CU (R0/R2-proven for k_stats)
#define NWAVES (STATS_BLOCKS*4)   // 4096 stats waves
#define PER ((CHUNKS + NWAVES - 1)/NWAVES)   // 105 chunks per stats-wave run

#define SCALE_BLOCKS 2048         // 8 blocks/CU; wave PAIR mirrors one stats run

#define NREP   16                 // sum/sq accumulator replicas (atomic de-contention)
// ws layout (floats): gsum[NREP][64] @0, gsq[NREP][64] @1024, gn[8][8] ints @2048
#define WS_FLOATS (NREP*64*2 + 64)

typedef float floatx4 __attribute__((ext_vector_type(4)));

// ---------------- K1: per-channel sum/sumsq + per-batch mask count ----------------
// R0/R2 contiguous-run structure (known-good), plus:
//  (a) 16-way REPLICATED atomics: ~8 consecutive waves share a plane -> 8-way
//      same-address atomic collisions cost ~15-40us (calibrated from R1's +136us
//      at 87k extra pairs). Replica gw&15 spreads them across 16 lines.
//  (b) 8-deep load pipeline with 4 independent (s,q) accumulator pairs: old
//      unroll-4 + single serial q-chain drained vmcnt each group (~2-3 loads in
//      flight). Now 8 loads issue before first consume -> 8KB/wave in flight.
// Mask: occ zeroes all channels of a pixel together -> channel 0 alone decides.
// Plain loads: we WANT x resident in L3 for k_scale + next iteration.
__global__ __launch_bounds__(256, 4) void k_stats(const floatx4* __restrict__ x4,
                                                  float* __restrict__ gsum,
                                                  float* __restrict__ gsq,
                                                  int* __restrict__ gn) {
    const int lane = threadIdx.x & 63;
    const int gw   = blockIdx.x * 4 + (threadIdx.x >> 6);   // global wave id
    const int rep  = gw & (NREP - 1);
    int c0 = gw * PER;
    const int c1 = min(c0 + PER, CHUNKS);

    while (c0 < c1) {
        const int plane = (int)((unsigned)c0 / CPP);        // wave-uniform
        const int run   = min(c1, (plane + 1) * CPP);       // end of this plane-run
        const bool isC0 = (plane & 63) == 0;

        float s0 = 0.f, s1 = 0.f, s2 = 0.f, s3 = 0.f;
        float q0 = 0.f, q1 = 0.f, q2 = 0.f, q3 = 0.f;
        int cnt = 0;
        const floatx4* p = x4 + (size_t)c0 * 64 + lane;
        const int n = run - c0;
        int k = 0;
        for (; k + 8 <= n; k += 8) {
            const floatx4 v0 = p[(size_t)(k + 0) * 64];
            const floatx4 v1 = p[(size_t)(k + 1) * 64];
            const floatx4 v2 = p[(size_t)(k + 2) * 64];
            const floatx4 v3 = p[(size_t)(k + 3) * 64];
            const floatx4 v4 = p[(size_t)(k + 4) * 64];
            const floatx4 v5 = p[(size_t)(k + 5) * 64];
            const floatx4 v6 = p[(size_t)(k + 6) * 64];
            const floatx4 v7 = p[(size_t)(k + 7) * 64];
            s0 += (v0.x + v0.y) + (v0.z + v0.w);
            s1 += (v1.x + v1.y) + (v1.z + v1.w);
            s2 += (v2.x + v2.y) + (v2.z + v2.w);
            s3 += (v3.x + v3.y) + (v3.z + v3.w);
            q0 = fmaf(v0.w, v0.w, fmaf(v0.z, v0.z, fmaf(v0.y, v0.y, fmaf(v0.x, v0.x, q0))));
            q1 = fmaf(v1.w, v1.w, fmaf(v1.z, v1.z, fmaf(v1.y, v1.y, fmaf(v1.x, v1.x, q1))));
            q2 = fmaf(v2.w, v2.w, fmaf(v2.z, v2.z, fmaf(v2.y, v2.y, fmaf(v2.x, v2.x, q2))));
            q3 = fmaf(v3.w, v3.w, fmaf(v3.z, v3.z, fmaf(v3.y, v3.y, fmaf(v3.x, v3.x, q3))));
            s0 += (v4.x + v4.y) + (v4.z + v4.w);
            s1 += (v5.x + v5.y) + (v5.z + v5.w);
            s2 += (v6.x + v6.y) + (v6.z + v6.w);
            s3 += (v7.x + v7.y) + (v7.z + v7.w);
            q0 = fmaf(v4.w, v4.w, fmaf(v4.z, v4.z, fmaf(v4.y, v4.y, fmaf(v4.x, v4.x, q0))));
            q1 = fmaf(v5.w, v5.w, fmaf(v5.z, v5.z, fmaf(v5.y, v5.y, fmaf(v5.x, v5.x, q1))));
            q2 = fmaf(v6.w, v6.w, fmaf(v6.z, v6.z, fmaf(v6.y, v6.y, fmaf(v6.x, v6.x, q2))));
            q3 = fmaf(v7.w, v7.w, fmaf(v7.z, v7.z, fmaf(v7.y, v7.y, fmaf(v7.x, v7.x, q3))));
            if (isC0) {
                cnt += (v0.x != 0.f) + (v0.y != 0.f) + (v0.z != 0.f) + (v0.w != 0.f);
                cnt += (v1.x != 0.f) + (v1.y != 0.f) + (v1.z != 0.f) + (v1.w != 0.f);
                cnt += (v2.x != 0.f) + (v2.y != 0.f) + (v2.z != 0.f) + (v2.w != 0.f);
                cnt += (v3.x != 0.f) + (v3.y != 0.f) + (v3.z != 0.f) + (v3.w != 0.f);
                cnt += (v4.x != 0.f) + (v4.y != 0.f) + (v4.z != 0.f) + (v4.w != 0.f);
                cnt += (v5.x != 0.f) + (v5.y != 0.f) + (v5.z != 0.f) + (v5.w != 0.f);
                cnt += (v6.x != 0.f) + (v6.y != 0.f) + (v6.z != 0.f) + (v6.w != 0.f);
                cnt += (v7.x != 0.f) + (v7.y != 0.f) + (v7.z != 0.f) + (v7.w != 0.f);
            }
        }
        for (; k < n; ++k) {
            const floatx4 v = p[(size_t)k * 64];
            s0 += (v.x + v.y) + (v.z + v.w);
            q0 = fmaf(v.w, v.w, fmaf(v.z, v.z, fmaf(v.y, v.y, fmaf(v.x, v.x, q0))));
            if (isC0) cnt += (v.x != 0.f) + (v.y != 0.f) + (v.z != 0.f) + (v.w != 0.f);
        }
        float s = (s0 + s1) + (s2 + s3);
        float q = (q0 + q1) + (q2 + q3);
#pragma unroll
        for (int m = 1; m < 64; m <<= 1) {
            s += __shfl_xor(s, m, 64);
            q += __shfl_xor(q, m, 64);
        }
        if (isC0) {
#pragma unroll
            for (int m = 1; m < 64; m <<= 1) cnt += __shfl_xor(cnt, m, 64);
        }
        if (lane == 0) {
            atomicAdd(&gsum[rep * 64 + (plane & 63)], s);
            atomicAdd(&gsq[rep * 64 + (plane & 63)], q);
            if (isC0) atomicAdd(&gn[(rep & 7) * 8 + (plane >> 6)], cnt);
        }
        c0 = run;
    }
}

// ---------------- K2: finalize (prologue) + out = x * inv[c], MIRRORED reverse ------
// R2-proven (best round): NT load/store — x won't be re-read THIS iteration, out is
// write-once; NT keeps out from evicting x's L3 residency (R3 proved plain stores
// regress). Wave PAIR p mirrors stats run p tail-first, popping the LRU stack top.
__global__ __launch_bounds__(256, 8) void k_scale(const floatx4* __restrict__ x4,
                                                  floatx4* __restrict__ out4,
                                                  const float* __restrict__ gsum,
                                                  const float* __restrict__ gsq,
                                                  const int* __restrict__ gn) {
    __shared__ float sinv[64];
    const int tid = threadIdx.x;
    if (tid < 64) {
        const int c = tid;
        const float* x = (const float*)x4;
        float total = 0.f, S2 = 0.f;
#pragma unroll
        for (int r = 0; r < NREP; ++r) {
            total += gsum[r * 64 + c];
            S2    += gsq[r * 64 + c];
        }
        int nb[8];
        int N = 0;
#pragma unroll
        for (int b = 0; b < 8; ++b) {
            int v = 0;
#pragma unroll
            for (int r = 0; r < 8; ++r) v += gn[r * 8 + b];
            nb[b] = v;
            N = max(N, v);
        }
#pragma unroll
        for (int b = 0; b < 8; ++b) {
            const float pad = (float)(N - nb[b]);
            const float x00 = x[(size_t)(b * 64 + c) * WH];
            total = fmaf(pad, x00, total);
            S2    = fmaf(pad, x00 * x00, S2);
        }
        const float count = (float)(8 * N);
        const float mean  = total / count;
        const float var   = S2 / count - mean * mean;
        sinv[c] = 1.0f / sqrtf(var + 0.001f);
    }
    __syncthreads();

    const int lane = tid & 63;
    const int gw   = blockIdx.x * 4 + (tid >> 6);   // 0..8191
    const int run  = gw >> 1;                       // mirrors stats wave id 0..4095
    const int sub  = gw & 1;
    const int c0   = run * PER;
    const int c1   = min(c0 + PER, CHUNKS);
#pragma unroll 4
    for (int ch = c1 - 1 - sub; ch >= c0; ch -= 2) {
        const int plane = (int)((unsigned)ch / CPP);      // wave-uniform
        const float inv = sinv[plane & 63];
        const size_t i = (size_t)ch * 64 + lane;
        floatx4 v = __builtin_nontemporal_load(&x4[i]);
        v.x *= inv; v.y *= inv; v.z *= inv; v.w *= inv;
        __builtin_nontemporal_store(v, &out4[i]);
    }
}

extern "C" void kernel_launch(void* const* d_in, const int* in_sizes, int n_in,
                              void* d_out, int out_size, void* d_ws, size_t ws_size,
                              hipStream_t stream) {
    const float* x  = (const float*)d_in[0];
    float* out      = (float*)d_out;
    float* wsf      = (float*)d_ws;
    float* gsum     = wsf;                        // [NREP][64]
    float* gsq      = wsf + NREP * 64;            // [NREP][64]
    int*   gn       = (int*)(wsf + NREP * 128);   // [8][8]

    (void)hipMemsetAsync(d_ws, 0, WS_FLOATS * sizeof(float), stream);

    k_stats<<<STATS_BLOCKS, 256, 0, stream>>>((const floatx4*)x, gsum, gsq, gn);
    k_scale<<<SCALE_BLOCKS, 256, 0, stream>>>((const floatx4*)x, (floatx4*)out,
                                              gsum, gsq, gn);
}

// Round 6
// 760.936 us; speedup vs baseline: 1.0564x; 1.0058x over previous
//
#include <hip/hip_runtime.h>

// Problem constants (B=8, C=64, W=496, H=432)
#define WH      214272            // 496*432 pixels per (b,c) plane
#define GPB     53568             // WH/4 float4 groups per plane (mult of 64)
#define TOTAL4  (512*GPB)         // all float4 elements = 27,426,816
#define CHUNKS  (TOTAL4/64)       // 64-float4 (1 KB/wave) chunks = 428544
#define CPP     (GPB/64)          // chunks per plane = 837

#define BLOCKS  2048              // 8 blocks/CU -> 32 waves/CU, both kernels
#define NW      (BLOCKS*4)        // 8192 waves
#define PER     ((CHUNKS + NW - 1)/NW)   // 53 chunks per wave run
#define NTCH    25                // leading NT chunks/run; trailing 28 plain ≈232MB (<256MB L3)

#define NREP    16                // accumulator replicas (atomic de-contention, R4-proven)
// ws layout (floats): gsum[NREP][64] @0, gsq[NREP][64] @1024, gn[8][8] ints @2048
#define WS_FLOATS (NREP*64*2 + 64)

typedef float floatx4 __attribute__((ext_vector_type(4)));

// Reverse-order 6-deep pipelined accumulate over chunks [lo,hi) of `base` (lane folded in).
// NT=true: non-temporal loads (no L3 allocation -> never evicts the resident tail).
template<bool NT>
__device__ __forceinline__ void sweep(const floatx4* __restrict__ base, int lo, int hi,
                                      float& s0, float& s1, float& s2, float& s3,
                                      float& q0, float& q1, float& q2, float& q3,
                                      int& cnt, const bool isC0) {
    int k = hi;
    while (k - 6 >= lo) {
        k -= 6;
        floatx4 v0, v1, v2, v3, v4, v5;
        if (NT) {
            v0 = __builtin_nontemporal_load(&base[(size_t)(k + 5) * 64]);
            v1 = __builtin_nontemporal_load(&base[(size_t)(k + 4) * 64]);
            v2 = __builtin_nontemporal_load(&base[(size_t)(k + 3) * 64]);
            v3 = __builtin_nontemporal_load(&base[(size_t)(k + 2) * 64]);
            v4 = __builtin_nontemporal_load(&base[(size_t)(k + 1) * 64]);
            v5 = __builtin_nontemporal_load(&base[(size_t)(k + 0) * 64]);
        } else {
            v0 = base[(size_t)(k + 5) * 64];
            v1 = base[(size_t)(k + 4) * 64];
            v2 = base[(size_t)(k + 3) * 64];
            v3 = base[(size_t)(k + 2) * 64];
            v4 = base[(size_t)(k + 1) * 64];
            v5 = base[(size_t)(k + 0) * 64];
        }
        s0 += (v0.x + v0.y) + (v0.z + v0.w);
        s1 += (v1.x + v1.y) + (v1.z + v1.w);
        s2 += (v2.x + v2.y) + (v2.z + v2.w);
        s3 += (v3.x + v3.y) + (v3.z + v3.w);
        q0 = fmaf(v0.w, v0.w, fmaf(v0.z, v0.z, fmaf(v0.y, v0.y, fmaf(v0.x, v0.x, q0))));
        q1 = fmaf(v1.w, v1.w, fmaf(v1.z, v1.z, fmaf(v1.y, v1.y, fmaf(v1.x, v1.x, q1))));
        q2 = fmaf(v2.w, v2.w, fmaf(v2.z, v2.z, fmaf(v2.y, v2.y, fmaf(v2.x, v2.x, q2))));
        q3 = fmaf(v3.w, v3.w, fmaf(v3.z, v3.z, fmaf(v3.y, v3.y, fmaf(v3.x, v3.x, q3))));
        s0 += (v4.x + v4.y) + (v4.z + v4.w);
        s1 += (v5.x + v5.y) + (v5.z + v5.w);
        q0 = fmaf(v4.w, v4.w, fmaf(v4.z, v4.z, fmaf(v4.y, v4.y, fmaf(v4.x, v4.x, q0))));
        q1 = fmaf(v5.w, v5.w, fmaf(v5.z, v5.z, fmaf(v5.y, v5.y, fmaf(v5.x, v5.x, q1))));
        if (isC0) {
            cnt += (v0.x != 0.f) + (v0.y != 0.f) + (v0.z != 0.f) + (v0.w != 0.f);
            cnt += (v1.x != 0.f) + (v1.y != 0.f) + (v1.z != 0.f) + (v1.w != 0.f);
            cnt += (v2.x != 0.f) + (v2.y != 0.f) + (v2.z != 0.f) + (v2.w != 0.f);
            cnt += (v3.x != 0.f) + (v3.y != 0.f) + (v3.z != 0.f) + (v3.w != 0.f);
            cnt += (v4.x != 0.f) + (v4.y != 0.f) + (v4.z != 0.f) + (v4.w != 0.f);
            cnt += (v5.x != 0.f) + (v5.y != 0.f) + (v5.z != 0.f) + (v5.w != 0.f);
        }
    }
    while (k > lo) {
        --k;
        floatx4 v;
        if (NT) v = __builtin_nontemporal_load(&base[(size_t)k * 64]);
        else    v = base[(size_t)k * 64];
        s0 += (v.x + v.y) + (v.z + v.w);
        q0 = fmaf(v.w, v.w, fmaf(v.z, v.z, fmaf(v.y, v.y, fmaf(v.x, v.x, q0))));
        if (isC0) cnt += (v.x != 0.f) + (v.y != 0.f) + (v.z != 0.f) + (v.w != 0.f);
    }
}

// ---------------- K1: per-channel sum/sumsq + per-batch mask count ----------------
// Changes vs R4 (k_stats was ~143us = 3.1 TB/s pure read; latency + L3-thrash bound):
//  (a) 32 waves/CU (was 16): 2x memory concurrency. 6-deep pipeline to fit 64 VGPR.
//  (b) STABLE L3 RESIDENCY: trailing 28/53 chunks of each run use PLAIN loads
//      (~232MB, fits 256MB L3) and are read FIRST (reverse walk); leading 25/53
//      use NT loads (no allocation -> the resident tail is NEVER evicted: k_scale
//      and the NT front don't allocate either). Steady state: tail = L3 hit,
//      front = clean HBM stream. Fixes the ~50% thrash (FETCH was 214MB of 438).
// Mask: occ zeroes all channels of a pixel together -> channel 0 alone decides.
__global__ __launch_bounds__(256, 8) void k_stats(const floatx4* __restrict__ x4,
                                                  float* __restrict__ gsum,
                                                  float* __restrict__ gsq,
                                                  int* __restrict__ gn) {
    const int lane = threadIdx.x & 63;
    const int gw   = blockIdx.x * 4 + (threadIdx.x >> 6);   // global wave id
    const int rep  = gw & (NREP - 1);
    const int c0   = gw * PER;
    const int c1   = min(c0 + PER, CHUNKS);
    if (c0 >= c1) return;
    const int split = c0 + NTCH;            // [c0,split): NT front; [split,c1): plain tail
    const floatx4* base = x4 + lane;

    int e = c1;                             // walk plane-runs high -> low
    while (e > c0) {
        const int plane = (int)((unsigned)(e - 1) / CPP);   // wave-uniform
        const int s = max(c0, plane * CPP);
        const bool isC0 = (plane & 63) == 0;

        float s0 = 0.f, s1 = 0.f, s2 = 0.f, s3 = 0.f;
        float q0 = 0.f, q1 = 0.f, q2 = 0.f, q3 = 0.f;
        int cnt = 0;

        const int pl = max(s, split);       // plain sub-range [pl, e)
        if (e > pl)
            sweep<false>(base, pl, e, s0, s1, s2, s3, q0, q1, q2, q3, cnt, isC0);
        const int nthi = min(e, split);     // NT sub-range [s, nthi)
        if (nthi > s)
            sweep<true>(base, s, nthi, s0, s1, s2, s3, q0, q1, q2, q3, cnt, isC0);

        float ss = (s0 + s1) + (s2 + s3);
        float qq = (q0 + q1) + (q2 + q3);
#pragma unroll
        for (int m = 1; m < 64; m <<= 1) {
            ss += __shfl_xor(ss, m, 64);
            qq += __shfl_xor(qq, m, 64);
        }
        if (isC0) {
#pragma unroll
            for (int m = 1; m < 64; m <<= 1) cnt += __shfl_xor(cnt, m, 64);
        }
        if (lane == 0) {
            atomicAdd(&gsum[rep * 64 + (plane & 63)], ss);
            atomicAdd(&gsq[rep * 64 + (plane & 63)], qq);
            if (isC0) atomicAdd(&gn[(rep & 7) * 8 + (plane >> 6)], cnt);
        }
        e = s;
    }
}

// ---------------- K2: finalize (prologue) + out = x * inv[c], MIRRORED reverse ------
// R2/R4-proven: NT load/store (R3 proved plain stores regress — they evict x's L3
// residency). Wave gw mirrors stats wave gw's run, walked tail-first: the plain
// (resident) tail chunks are consumed as L3 hits before the NT-front misses.
__global__ __launch_bounds__(256, 8) void k_scale(const floatx4* __restrict__ x4,
                                                  floatx4* __restrict__ out4,
                                                  const float* __restrict__ gsum,
                                                  const float* __restrict__ gsq,
                                                  const int* __restrict__ gn) {
    __shared__ float sinv[64];
    const int tid = threadIdx.x;
    if (tid < 64) {
        const int c = tid;
        const float* x = (const float*)x4;
        float total = 0.f, S2 = 0.f;
#pragma unroll
        for (int r = 0; r < NREP; ++r) {
            total += gsum[r * 64 + c];
            S2    += gsq[r * 64 + c];
        }
        int nb[8];
        int N = 0;
#pragma unroll
        for (int b = 0; b < 8; ++b) {
            int v = 0;
#pragma unroll
            for (int r = 0; r < 8; ++r) v += gn[r * 8 + b];
            nb[b] = v;
            N = max(N, v);
        }
#pragma unroll
        for (int b = 0; b < 8; ++b) {
            const float pad = (float)(N - nb[b]);
            const float x00 = x[(size_t)(b * 64 + c) * WH];
            total = fmaf(pad, x00, total);
            S2    = fmaf(pad, x00 * x00, S2);
        }
        const float count = (float)(8 * N);
        const float mean  = total / count;
        const float var   = S2 / count - mean * mean;
        sinv[c] = 1.0f / sqrtf(var + 0.001f);
    }
    __syncthreads();

    const int lane = tid & 63;
    const int gw   = blockIdx.x * 4 + (tid >> 6);   // 0..8191, mirrors stats wave
    const int c0   = gw * PER;
    const int c1   = min(c0 + PER, CHUNKS);
#pragma unroll 4
    for (int ch = c1 - 1; ch >= c0; --ch) {
        const int plane = (int)((unsigned)ch / CPP);      // wave-uniform
        const float inv = sinv[plane & 63];
        const size_t i = (size_t)ch * 64 + lane;
        floatx4 v = __builtin_nontemporal_load(&x4[i]);
        v.x *= inv; v.y *= inv; v.z *= inv; v.w *= inv;
        __builtin_nontemporal_store(v, &out4[i]);
    }
}

extern "C" void kernel_launch(void* const* d_in, const int* in_sizes, int n_in,
                              void* d_out, int out_size, void* d_ws, size_t ws_size,
                              hipStream_t stream) {
    const float* x  = (const float*)d_in[0];
    float* out      = (float*)d_out;
    float* wsf      = (float*)d_ws;
    float* gsum     = wsf;                        // [NREP][64]
    float* gsq      = wsf + NREP * 64;            // [NREP][64]
    int*   gn       = (int*)(wsf + NREP * 128);   // [8][8]

    (void)hipMemsetAsync(d_ws, 0, WS_FLOATS * sizeof(float), stream);

    k_stats<<<BLOCKS, 256, 0, stream>>>((const floatx4*)x, gsum, gsq, gn);
    k_scale<<<BLOCKS, 256, 0, stream>>>((const floatx4*)x, (floatx4*)out,
                                        gsum, gsq, gn);
}